// Round 9
// baseline (441.139 us; speedup 1.0000x reference)
//
#include <hip/hip_runtime.h>
#include <cmath>

#define NN 4096
#define KK 32
#define DD 256
#define HH 128
#define G3 384   // 3*H
#define CH 16    // xw0 chunk steps staged in LDS

typedef __attribute__((ext_vector_type(8))) _Float16 h8;
typedef __attribute__((ext_vector_type(4))) float f32x4;

// ---------------------------------------------------------------------------
// Kernel 1 (proven R8): fused setup. Block 0: order/pos/len + prefix + scale.
// Blocks 1..18: pack {W_hh0, W_ih1, W_hh1} into f16 B-fragments.
// Pack layout: [mat(3)][nt(24)][kt(4)][lane(64)][j(8)];
// B[k][n]: n = nt*16 + (lane&15), k = kt*32 + (lane>>4)*8 + j.
// ---------------------------------------------------------------------------
__global__ __launch_bounds__(1024) void setup_k(
    const int* __restrict__ labels, const float* __restrict__ lin_v,
    const float* __restrict__ lin_g,
    const float* __restrict__ Whh0, const float* __restrict__ Wih1,
    const float* __restrict__ Whh1,
    int* __restrict__ order, int* __restrict__ pos, int* __restrict__ len,
    int* __restrict__ starts, float* __restrict__ scale,
    _Float16* __restrict__ P) {
  if (blockIdx.x != 0) {
    const int gid = (int)(blockIdx.x - 1) * 1024 + threadIdx.x;  // 18432
    if (gid >= 18432) return;
    const int lane = gid & 63;
    const int kt = (gid >> 6) & 3;
    const int nt = (gid >> 8) % 24;
    const int mat = (gid >> 8) / 24;
    const float* W = (mat == 0) ? Whh0 : (mat == 1 ? Wih1 : Whh1);
    const int n = nt * 16 + (lane & 15);
    const int kbase = kt * 32 + (lane >> 4) * 8;
    _Float16* dst = P + (size_t)gid * 8;
#pragma unroll
    for (int j = 0; j < 8; ++j) dst[j] = (_Float16)W[(size_t)n * HH + kbase + j];
    return;
  }
  const int t = threadIdx.x;
  const int wv = t >> 6, lane = t & 63;
  __shared__ int lens_s[KK];
  for (int cc = 0; cc < 2; ++cc) {
    const int c = wv * 2 + cc;
    int count = 0;
    for (int base = 0; base < NN; base += 64) {
      const int i = base + lane;
      const bool f = (labels[i] == c);
      const unsigned long long m = __ballot(f);
      if (f) {
        const int p = count + __popcll(m & ((1ull << lane) - 1ull));
        order[c * NN + p] = i;
        pos[i] = p;
      }
      count += __popcll(m);
    }
    if (lane == 0) { lens_s[c] = count; len[c] = count; }
  }
  __syncthreads();
  if (wv == 0) {
    int lm = 0;
    if (lane < KK) { const int l = lens_s[lane]; lm = (l > 0) ? l : 1; }
    int inc = lm;
    for (int off = 1; off < KK; off <<= 1) {
      const int o = __shfl_up(inc, off);
      if (lane >= off) inc += o;
    }
    if (lane < KK) starts[lane] = inc - lm;
    if (lane == KK - 1) starts[KK] = inc;
  } else if (wv == 1) {
    float s = 0.f;
    for (int j = lane; j < G3; j += 64) { const float v = lin_v[j]; s += v * v; }
    for (int off = 32; off; off >>= 1) s += __shfl_down(s, off);
    if (lane == 0) scale[0] = lin_g[0] / sqrtf(s);
  }
}

// ---------------------------------------------------------------------------
// Kernel 2 (proven): out[slot(i)][g] = bias[g] + sum_d X[i][d]*W[g][d]
// ---------------------------------------------------------------------------
__global__ __launch_bounds__(256) void gemm_ih_k(
    const float* __restrict__ X, const float* __restrict__ W,
    const float* __restrict__ bias,
    const int* __restrict__ labels, const int* __restrict__ pos,
    const int* __restrict__ starts, float* __restrict__ out) {
  __shared__ float Xs[16][132];
  __shared__ float Ws[16][68];
  const int i0 = blockIdx.x * 128;
  const int g0 = blockIdx.y * 64;
  const int t  = threadIdx.x;
  const int it = t & 15;
  const int gt = t >> 4;
  float acc[8][4] = {};
  for (int k0 = 0; k0 < DD; k0 += 16) {
#pragma unroll
    for (int l = 0; l < 2; ++l) {
      const int u = t * 2 + l;
      const int r = u >> 2;
      const int cq = u & 3;
      const float4 f = *(const float4*)(X + (size_t)(i0 + r) * DD + k0 + cq * 4);
      Xs[cq * 4 + 0][r] = f.x; Xs[cq * 4 + 1][r] = f.y;
      Xs[cq * 4 + 2][r] = f.z; Xs[cq * 4 + 3][r] = f.w;
    }
    {
      const int r = t >> 2;
      const int cq = t & 3;
      const float4 f = *(const float4*)(W + (size_t)(g0 + r) * DD + k0 + cq * 4);
      Ws[cq * 4 + 0][r] = f.x; Ws[cq * 4 + 1][r] = f.y;
      Ws[cq * 4 + 2][r] = f.z; Ws[cq * 4 + 3][r] = f.w;
    }
    __syncthreads();
#pragma unroll
    for (int k = 0; k < 16; ++k) {
      float a[8], b[4];
#pragma unroll
      for (int x = 0; x < 8; ++x) a[x] = Xs[k][it * 8 + x];
#pragma unroll
      for (int y = 0; y < 4; ++y) b[y] = Ws[k][gt * 4 + y];
#pragma unroll
      for (int x = 0; x < 8; ++x)
#pragma unroll
        for (int y = 0; y < 4; ++y)
          acc[x][y] += a[x] * b[y];
    }
    __syncthreads();
  }
  const float4 bs = *(const float4*)(bias + g0 + gt * 4);
#pragma unroll
  for (int x = 0; x < 8; ++x) {
    const int gi = i0 + it * 8 + x;
    const int slot = starts[labels[gi]] + pos[gi];
    float4 o;
    o.x = acc[x][0] + bs.x; o.y = acc[x][1] + bs.y;
    o.z = acc[x][2] + bs.z; o.w = acc[x][3] + bs.w;
    *(float4*)(out + (size_t)slot * G3 + g0 + gt * 4) = o;
  }
}

// ---------------------------------------------------------------------------
// Kernel 3: FUSED 2-layer GRU, 4 MEGA-WAVES (1/SIMD) per cluster block.
// Wave v owns gate slice {32v..32v+31} of ALL THREE matvecs:
//   18 chains x 4 kt = 72 MFMAs/wave/step (L0-hw, xw1, L1-hw; 6 tiles each),
//   both gate computations, and the xw1 publish — all wave-local.
// Gate VALU co-issues on the VALU pipe while the MFMA pipe drains.
// A row0 = h_hi, row1 = h_lo (f16 split, full-precision h). 1 barrier/step.
// Pipeline (as R8): L0 at iter i -> h1(i); xw1(i-1) at iter i; L1 at iter i
// -> h2(i-2). Loop runs Lr+2 iters. Tail: scoring for this cluster.
// ---------------------------------------------------------------------------
__global__ __launch_bounds__(256, 1) void gru_fused_k(
    const float* __restrict__ xw0,          // sorted [Mtot+2CH][384] fp32
    const _Float16* __restrict__ pack,      // [3][24][4][64][8] f16 frags
    const float* __restrict__ b_hh0, const float* __restrict__ b_ih0,
    const float* __restrict__ b_ih1, const float* __restrict__ b_hh1,
    const int* __restrict__ starts, const int* __restrict__ len,
    const int* __restrict__ order, const float* __restrict__ sent,
    const float* __restrict__ lin_v, const float* __restrict__ scale,
    const float* __restrict__ lin_b, float* __restrict__ out) {
  const int c = blockIdx.x;
  const int t = threadIdx.x;
  const int wv = t >> 6, lane = t & 63;
  const int v = wv;
  // ---- preload B fragments: 18 chains (compiler parks these in AGPRs) -----
  h8 B0[6][4], BX[6][4], B1[6][4];
#pragma unroll
  for (int i = 0; i < 6; ++i) {
    const int nt = (i >> 1) * 8 + 2 * v + (i & 1);
#pragma unroll
    for (int kt = 0; kt < 4; ++kt) {
      const size_t idx = ((size_t)(nt * 4 + kt) * 64 + lane) * 8;
      B0[i][kt] = *(const h8*)(pack + idx);
      BX[i][kt] = *(const h8*)(pack + (size_t)(24 * 4 * 64 * 8) + idx);
      B1[i][kt] = *(const h8*)(pack + (size_t)(2 * 24 * 4 * 64 * 8) + idx);
    }
  }
  const int L = len[c], start = starts[c];
  const int Lr = (L > 0) ? L : 1;
  const bool use_bih0 = (L == 0);
  // ---- LDS ----------------------------------------------------------------
  __shared__ __align__(16) float xwbuf[2 * CH * G3];     // 48 KB dbuf chunks
  __shared__ __align__(16) _Float16 hp1[2][2][HH];       // [par][hi/lo]
  __shared__ __align__(16) _Float16 hp2[2][2][HH];
  __shared__ float xw1buf[2][G3];
  __shared__ float ce_s[HH];
  __shared__ float vbuf[G3];
  __shared__ float sc_s[2048];
  __shared__ float sc_red;
  if (t < HH) {
    hp1[0][0][t] = (_Float16)0.f; hp1[0][1][t] = (_Float16)0.f;
    hp2[0][0][t] = (_Float16)0.f; hp2[0][1][t] = (_Float16)0.f;
    hp2[1][0][t] = (_Float16)0.f; hp2[1][1][t] = (_Float16)0.f;
  }
  // prologue: stage chunk 0 into buffer 0
  if (!use_bih0) {
    const float4* src = (const float4*)(xw0 + (size_t)start * G3);
    float4* dst = (float4*)xwbuf;
#pragma unroll
    for (int u = 0; u < 6; ++u) dst[t + u * 256] = src[t + u * 256];
  }
  // ---- per-lane gate constants (lanes 0..15) ------------------------------
  const int t0 = 32 * v + (lane & 15), t1 = t0 + 16;
  float b0r0 = 0.f, b0z0 = 0.f, b0n0 = 0.f, b0r1 = 0.f, b0z1 = 0.f, b0n1 = 0.f;
  float f0r0 = 0.f, f0z0 = 0.f, f0n0 = 0.f, f0r1 = 0.f, f0z1 = 0.f, f0n1 = 0.f;
  float b1r0 = 0.f, b1z0 = 0.f, b1n0 = 0.f, b1r1 = 0.f, b1z1 = 0.f, b1n1 = 0.f;
  float i1r0 = 0.f, i1z0 = 0.f, i1n0 = 0.f, i1r1 = 0.f, i1z1 = 0.f, i1n1 = 0.f;
  float h1a = 0.f, h1b = 0.f, h2a = 0.f, h2b = 0.f;
  if (lane < 16) {
    b0r0 = b_hh0[t0]; b0z0 = b_hh0[HH + t0]; b0n0 = b_hh0[2 * HH + t0];
    b0r1 = b_hh0[t1]; b0z1 = b_hh0[HH + t1]; b0n1 = b_hh0[2 * HH + t1];
    b1r0 = b_hh1[t0]; b1z0 = b_hh1[HH + t0]; b1n0 = b_hh1[2 * HH + t0];
    b1r1 = b_hh1[t1]; b1z1 = b_hh1[HH + t1]; b1n1 = b_hh1[2 * HH + t1];
    i1r0 = b_ih1[t0]; i1z0 = b_ih1[HH + t0]; i1n0 = b_ih1[2 * HH + t0];
    i1r1 = b_ih1[t1]; i1z1 = b_ih1[HH + t1]; i1n1 = b_ih1[2 * HH + t1];
    if (use_bih0) {
      f0r0 = b_ih0[t0]; f0z0 = b_ih0[HH + t0]; f0n0 = b_ih0[2 * HH + t0];
      f0r1 = b_ih0[t1]; f0z1 = b_ih0[HH + t1]; f0n1 = b_ih0[2 * HH + t1];
    }
  }
  __syncthreads();   // init + chunk-0 staging visible
  const int q = lane >> 4;
  const int hs = ((lane & 15) == 0) ? 0 : 1;   // A row0 = h_hi, rows>=1 = h_lo
  for (int iter = 0; iter < Lr + 2; ++iter) {
    const int par = iter & 1;
    // ---- prefetch next xw0 chunk into the other buffer -------------------
    if (!use_bih0 && (iter & (CH - 1)) == 0 && iter + CH < Lr) {
      const float4* src = (const float4*)(xw0 + (size_t)(start + iter + CH) * G3);
      float4* dst = (float4*)(xwbuf + ((((iter >> 4) + 1) & 1) ? CH * G3 : 0));
#pragma unroll
      for (int u = 0; u < 6; ++u) dst[t + u * 256] = src[t + u * 256];
    }
    // ---- A fragments (h1 and h2, hi/lo planes) ---------------------------
    h8 A1[4], A2[4];
    {
      const _Float16* h1base = hp1[par][hs];
      const _Float16* h2base = hp2[par][hs];
#pragma unroll
      for (int kt = 0; kt < 4; ++kt) {
        A1[kt] = *(const h8*)(h1base + kt * 32 + q * 8);
        A2[kt] = *(const h8*)(h2base + kt * 32 + q * 8);
      }
    }
    // ---- 72 MFMAs: L0-hw, L1-hw, xw1 (18 chains of 4) --------------------
    f32x4 a0[6], a1[6], ax[6];
#pragma unroll
    for (int i = 0; i < 6; ++i) {
      f32x4 a = {0.f, 0.f, 0.f, 0.f};
#pragma unroll
      for (int kt = 0; kt < 4; ++kt)
        a = __builtin_amdgcn_mfma_f32_16x16x32_f16(A1[kt], B0[i][kt], a, 0, 0, 0);
      a0[i] = a;
    }
#pragma unroll
    for (int i = 0; i < 6; ++i) {
      f32x4 a = {0.f, 0.f, 0.f, 0.f};
#pragma unroll
      for (int kt = 0; kt < 4; ++kt)
        a = __builtin_amdgcn_mfma_f32_16x16x32_f16(A2[kt], B1[i][kt], a, 0, 0, 0);
      a1[i] = a;
    }
#pragma unroll
    for (int i = 0; i < 6; ++i) {
      f32x4 a = {0.f, 0.f, 0.f, 0.f};
#pragma unroll
      for (int kt = 0; kt < 4; ++kt)
        a = __builtin_amdgcn_mfma_f32_16x16x32_f16(A1[kt], BX[i][kt], a, 0, 0, 0);
      ax[i] = a;
    }
    // ---- gate/publish phase (lanes 0..15) --------------------------------
    if (lane < 16) {
      if (iter < Lr) {                       // L0 gates -> h1(iter)
        float xr0, xz0, xn0, xr1, xz1, xn1;
        if (use_bih0) {
          xr0 = f0r0; xz0 = f0z0; xn0 = f0n0;
          xr1 = f0r1; xz1 = f0z1; xn1 = f0n1;
        } else {
          const float* xrow = xwbuf + ((iter >> 4) & 1) * (CH * G3)
                                    + (iter & (CH - 1)) * G3;
          xr0 = xrow[t0]; xz0 = xrow[HH + t0]; xn0 = xrow[2 * HH + t0];
          xr1 = xrow[t1]; xz1 = xrow[HH + t1]; xn1 = xrow[2 * HH + t1];
        }
        const float hwr0 = a0[0][0] + a0[0][1];
        const float hwr1 = a0[1][0] + a0[1][1];
        const float hwz0 = a0[2][0] + a0[2][1];
        const float hwz1 = a0[3][0] + a0[3][1];
        const float hwn0 = a0[4][0] + a0[4][1];
        const float hwn1 = a0[5][0] + a0[5][1];
        const float r0 = 1.f / (1.f + __expf(-(xr0 + b0r0 + hwr0)));
        const float z0 = 1.f / (1.f + __expf(-(xz0 + b0z0 + hwz0)));
        const float r1 = 1.f / (1.f + __expf(-(xr1 + b0r1 + hwr1)));
        const float z1 = 1.f / (1.f + __expf(-(xz1 + b0z1 + hwz1)));
        float tg0 = xn0 + r0 * (b0n0 + hwn0);
        float tg1 = xn1 + r1 * (b0n1 + hwn1);
        tg0 = fminf(fmaxf(tg0, -15.f), 15.f);
        tg1 = fminf(fmaxf(tg1, -15.f), 15.f);
        const float e0 = __expf(2.f * tg0), e1 = __expf(2.f * tg1);
        const float n0 = (e0 - 1.f) / (e0 + 1.f);
        const float n1 = (e1 - 1.f) / (e1 + 1.f);
        h1a = (1.f - z0) * n0 + z0 * h1a;
        h1b = (1.f - z1) * n1 + z1 * h1b;
        const _Float16 hiA = (_Float16)h1a, hiB = (_Float16)h1b;
        hp1[par ^ 1][0][t0] = hiA; hp1[par ^ 1][1][t0] = (_Float16)(h1a - (float)hiA);
        hp1[par ^ 1][0][t1] = hiB; hp1[par ^ 1][1][t1] = (_Float16)(h1b - (float)hiB);
      }
      if (iter >= 1 && iter <= Lr) {         // publish xw1(iter-1)
        float* xo = xw1buf[par ^ 1];
        xo[t0]          = ax[0][0] + ax[0][1];
        xo[t1]          = ax[1][0] + ax[1][1];
        xo[HH + t0]     = ax[2][0] + ax[2][1];
        xo[HH + t1]     = ax[3][0] + ax[3][1];
        xo[2 * HH + t0] = ax[4][0] + ax[4][1];
        xo[2 * HH + t1] = ax[5][0] + ax[5][1];
      }
      if (iter >= 2) {                       // L1 gates -> h2(iter-2)
        const float* xi = xw1buf[par];       // xw1(iter-2)
        const float xr0 = xi[t0] + i1r0;
        const float xz0 = xi[HH + t0] + i1z0;
        const float xn0 = xi[2 * HH + t0] + i1n0;
        const float xr1 = xi[t1] + i1r1;
        const float xz1 = xi[HH + t1] + i1z1;
        const float xn1 = xi[2 * HH + t1] + i1n1;
        const float hwr0 = a1[0][0] + a1[0][1];
        const float hwr1 = a1[1][0] + a1[1][1];
        const float hwz0 = a1[2][0] + a1[2][1];
        const float hwz1 = a1[3][0] + a1[3][1];
        const float hwn0 = a1[4][0] + a1[4][1];
        const float hwn1 = a1[5][0] + a1[5][1];
        const float r0 = 1.f / (1.f + __expf(-(xr0 + b1r0 + hwr0)));
        const float z0 = 1.f / (1.f + __expf(-(xz0 + b1z0 + hwz0)));
        const float r1 = 1.f / (1.f + __expf(-(xr1 + b1r1 + hwr1)));
        const float z1 = 1.f / (1.f + __expf(-(xz1 + b1z1 + hwz1)));
        float tg0 = xn0 + r0 * (b1n0 + hwn0);
        float tg1 = xn1 + r1 * (b1n1 + hwn1);
        tg0 = fminf(fmaxf(tg0, -15.f), 15.f);
        tg1 = fminf(fmaxf(tg1, -15.f), 15.f);
        const float e0 = __expf(2.f * tg0), e1 = __expf(2.f * tg1);
        const float n0 = (e0 - 1.f) / (e0 + 1.f);
        const float n1 = (e1 - 1.f) / (e1 + 1.f);
        h2a = (1.f - z0) * n0 + z0 * h2a;
        h2b = (1.f - z1) * n1 + z1 * h2b;
        const _Float16 hiA = (_Float16)h2a, hiB = (_Float16)h2b;
        hp2[par ^ 1][0][t0] = hiA; hp2[par ^ 1][1][t0] = (_Float16)(h2a - (float)hiA);
        hp2[par ^ 1][0][t1] = hiB; hp2[par ^ 1][1][t1] = (_Float16)(h2b - (float)hiB);
      }
    }
    __syncthreads();   // the ONLY barrier
  }
  // ---- scoring tail (cluster c's sentences) -------------------------------
  if (L == 0) return;
  if (lane < 16) { ce_s[t0] = h2a; ce_s[t1] = h2b; }
  if (t < HH) {
    vbuf[t] = lin_v[t];
    vbuf[HH + t] = lin_v[HH + t];
    vbuf[2 * HH + t] = lin_v[2 * HH + t];
  }
  __syncthreads();
  if (wv == 0) {   // ce . v[256:384] (per-cluster constant)
    float cd = ce_s[lane] * vbuf[DD + lane] + ce_s[64 + lane] * vbuf[DD + 64 + lane];
    for (int off = 32; off; off >>= 1) cd += __shfl_down(cd, off);
    if (lane == 0) sc_red = cd;
  }
  __syncthreads();
  const float cedot = sc_red;
  const float sc = scale[0], lb = lin_b[0];
  const int Lc = (L < 2048) ? L : 2048;
  for (int p = wv; p < Lc; p += 4) {
    const int i = order[c * NN + p];
    const float4 a = *(const float4*)(sent + (size_t)i * DD + lane * 4);
    const float4 b = ((const float4*)vbuf)[lane];
    float d = a.x * b.x + a.y * b.y + a.z * b.z + a.w * b.w;
    for (int off = 32; off; off >>= 1) d += __shfl_down(d, off);
    if (lane == 0) sc_s[p] = tanhf(sc * (d + cedot) + lb);
  }
  __syncthreads();
  if (wv == 0) {   // cluster sum -> 1/sum
    float s = 0.f;
    for (int p = lane; p < Lc; p += 64) s += sc_s[p];
    for (int off = 32; off; off >>= 1) s += __shfl_down(s, off);
    if (lane == 0) sc_red = 1.f / s;
  }
  __syncthreads();
  const float inv = sc_red;
  for (int p = t; p < Lc; p += 256) {
    const int i = order[c * NN + p];
    float ps = __expf(-(float)(i + 1) * 0.0625f);   // 1/4096^(1/3) == 1/16
    ps = fmaxf(0.5f, ps);
    out[i] = 0.5f * (sc_s[p] * inv) + 0.5f * ps;
  }
}

// ---------------------------------------------------------------------------
extern "C" void kernel_launch(void* const* d_in, const int* in_sizes, int n_in,
                              void* d_out, int out_size, void* d_ws, size_t ws_size,
                              hipStream_t stream) {
  const float* sent   = (const float*)d_in[0];
  const int*   labels = (const int*)d_in[1];
  const float* W_ih0  = (const float*)d_in[2];
  const float* W_hh0  = (const float*)d_in[3];
  const float* b_ih0  = (const float*)d_in[4];
  const float* b_hh0  = (const float*)d_in[5];
  const float* W_ih1  = (const float*)d_in[6];
  const float* W_hh1  = (const float*)d_in[7];
  const float* b_ih1  = (const float*)d_in[8];
  const float* b_hh1  = (const float*)d_in[9];
  const float* lin_v  = (const float*)d_in[10];
  const float* lin_g  = (const float*)d_in[11];
  const float* lin_b  = (const float*)d_in[12];
  float* out = (float*)d_out;

  char* ws = (char*)d_ws;
  size_t off = 0;
  auto alloc = [&](size_t bytes) -> void* {
    void* p = ws + off;
    off = (off + bytes + 255) & ~(size_t)255;
    return p;
  };
  int*   order  = (int*)  alloc((size_t)KK * NN * sizeof(int));
  int*   pos    = (int*)  alloc(NN * sizeof(int));
  int*   len    = (int*)  alloc(KK * sizeof(int));
  int*   starts = (int*)  alloc((KK + 1) * sizeof(int));
  float* scale  = (float*)alloc(sizeof(float));
  _Float16* pack = (_Float16*)alloc((size_t)18432 * 8 * sizeof(_Float16));
  float* xw     = (float*)alloc((size_t)(NN + KK + 2 * CH) * G3 * sizeof(float));
  (void)ws_size; (void)in_sizes; (void)n_in; (void)out_size;

  setup_k<<<dim3(19), dim3(1024), 0, stream>>>(
      labels, lin_v, lin_g, W_hh0, W_ih1, W_hh1,
      order, pos, len, starts, scale, pack);
  gemm_ih_k<<<dim3(32, 6), dim3(256), 0, stream>>>(
      sent, W_ih0, b_ih0, labels, pos, starts, xw);
  gru_fused_k<<<dim3(KK), dim3(256), 0, stream>>>(
      xw, pack, b_hh0, b_ih0, b_ih1, b_hh1, starts, len,
      order, sent, lin_v, scale, lin_b, out);
}

// Round 10
// 293.702 us; speedup vs baseline: 1.5020x; 1.5020x over previous
//
#include <hip/hip_runtime.h>
#include <cmath>

#define NN 4096
#define KK 32
#define DD 256
#define HH 128
#define G3 384   // 3*H
#define CH 16    // xw0 chunk steps staged in LDS
#define RH 136   // padded f16 stride of one h-half in the h1 ring

typedef __attribute__((ext_vector_type(8))) _Float16 h8;
typedef __attribute__((ext_vector_type(4))) float f32x4;

// ---------------------------------------------------------------------------
// Kernel 1 (proven R8): fused setup. Block 0: order/pos/len + prefix + scale.
// Blocks 1..18: pack {W_hh0, W_ih1, W_hh1} into f16 B-fragments.
// Pack layout: [mat(3)][nt(24)][kt(4)][lane(64)][j(8)];
// B[k][n]: n = nt*16 + (lane&15), k = kt*32 + (lane>>4)*8 + j.
// ---------------------------------------------------------------------------
__global__ __launch_bounds__(1024) void setup_k(
    const int* __restrict__ labels, const float* __restrict__ lin_v,
    const float* __restrict__ lin_g,
    const float* __restrict__ Whh0, const float* __restrict__ Wih1,
    const float* __restrict__ Whh1,
    int* __restrict__ order, int* __restrict__ pos, int* __restrict__ len,
    int* __restrict__ starts, float* __restrict__ scale,
    _Float16* __restrict__ P) {
  if (blockIdx.x != 0) {
    const int gid = (int)(blockIdx.x - 1) * 1024 + threadIdx.x;  // 18432
    if (gid >= 18432) return;
    const int lane = gid & 63;
    const int kt = (gid >> 6) & 3;
    const int nt = (gid >> 8) % 24;
    const int mat = (gid >> 8) / 24;
    const float* W = (mat == 0) ? Whh0 : (mat == 1 ? Wih1 : Whh1);
    const int n = nt * 16 + (lane & 15);
    const int kbase = kt * 32 + (lane >> 4) * 8;
    _Float16* dst = P + (size_t)gid * 8;
#pragma unroll
    for (int j = 0; j < 8; ++j) dst[j] = (_Float16)W[(size_t)n * HH + kbase + j];
    return;
  }
  const int t = threadIdx.x;
  const int wv = t >> 6, lane = t & 63;
  __shared__ int lens_s[KK];
  for (int cc = 0; cc < 2; ++cc) {
    const int c = wv * 2 + cc;
    int count = 0;
    for (int base = 0; base < NN; base += 64) {
      const int i = base + lane;
      const bool f = (labels[i] == c);
      const unsigned long long m = __ballot(f);
      if (f) {
        const int p = count + __popcll(m & ((1ull << lane) - 1ull));
        order[c * NN + p] = i;
        pos[i] = p;
      }
      count += __popcll(m);
    }
    if (lane == 0) { lens_s[c] = count; len[c] = count; }
  }
  __syncthreads();
  if (wv == 0) {
    int lm = 0;
    if (lane < KK) { const int l = lens_s[lane]; lm = (l > 0) ? l : 1; }
    int inc = lm;
    for (int off = 1; off < KK; off <<= 1) {
      const int o = __shfl_up(inc, off);
      if (lane >= off) inc += o;
    }
    if (lane < KK) starts[lane] = inc - lm;
    if (lane == KK - 1) starts[KK] = inc;
  } else if (wv == 1) {
    float s = 0.f;
    for (int j = lane; j < G3; j += 64) { const float v = lin_v[j]; s += v * v; }
    for (int off = 32; off; off >>= 1) s += __shfl_down(s, off);
    if (lane == 0) scale[0] = lin_g[0] / sqrtf(s);
  }
}

// ---------------------------------------------------------------------------
// Kernel 2 (proven): out[slot(i)][g] = bias[g] + sum_d X[i][d]*W[g][d]
// ---------------------------------------------------------------------------
__global__ __launch_bounds__(256) void gemm_ih_k(
    const float* __restrict__ X, const float* __restrict__ W,
    const float* __restrict__ bias,
    const int* __restrict__ labels, const int* __restrict__ pos,
    const int* __restrict__ starts, float* __restrict__ out) {
  __shared__ float Xs[16][132];
  __shared__ float Ws[16][68];
  const int i0 = blockIdx.x * 128;
  const int g0 = blockIdx.y * 64;
  const int t  = threadIdx.x;
  const int it = t & 15;
  const int gt = t >> 4;
  float acc[8][4] = {};
  for (int k0 = 0; k0 < DD; k0 += 16) {
#pragma unroll
    for (int l = 0; l < 2; ++l) {
      const int u = t * 2 + l;
      const int r = u >> 2;
      const int cq = u & 3;
      const float4 f = *(const float4*)(X + (size_t)(i0 + r) * DD + k0 + cq * 4);
      Xs[cq * 4 + 0][r] = f.x; Xs[cq * 4 + 1][r] = f.y;
      Xs[cq * 4 + 2][r] = f.z; Xs[cq * 4 + 3][r] = f.w;
    }
    {
      const int r = t >> 2;
      const int cq = t & 3;
      const float4 f = *(const float4*)(W + (size_t)(g0 + r) * DD + k0 + cq * 4);
      Ws[cq * 4 + 0][r] = f.x; Ws[cq * 4 + 1][r] = f.y;
      Ws[cq * 4 + 2][r] = f.z; Ws[cq * 4 + 3][r] = f.w;
    }
    __syncthreads();
#pragma unroll
    for (int k = 0; k < 16; ++k) {
      float a[8], b[4];
#pragma unroll
      for (int x = 0; x < 8; ++x) a[x] = Xs[k][it * 8 + x];
#pragma unroll
      for (int y = 0; y < 4; ++y) b[y] = Ws[k][gt * 4 + y];
#pragma unroll
      for (int x = 0; x < 8; ++x)
#pragma unroll
        for (int y = 0; y < 4; ++y)
          acc[x][y] += a[x] * b[y];
    }
    __syncthreads();
  }
  const float4 bs = *(const float4*)(bias + g0 + gt * 4);
#pragma unroll
  for (int x = 0; x < 8; ++x) {
    const int gi = i0 + it * 8 + x;
    const int slot = starts[labels[gi]] + pos[gi];
    float4 o;
    o.x = acc[x][0] + bs.x; o.y = acc[x][1] + bs.y;
    o.z = acc[x][2] + bs.z; o.w = acc[x][3] + bs.w;
    *(float4*)(out + (size_t)slot * G3 + g0 + gt * 4) = o;
  }
}

// ---------------------------------------------------------------------------
// Kernel 3: FUSED 2-layer GRU (R8 structure) + BATCHED xw1.
//   waves 0-3 (G0): per-step hw0 = W_hh0.h1(i-1) -> L0 gates -> h1(i),
//                   h1 written hi/lo into a 16-slot padded LDS ring.
//   waves 4-7 (G1): every 8 steps, xw1 for the last 8 steps as ONE 16-row
//                   GEMM (A rows = 8 steps x hi/lo from the ring; B = same
//                   W_ih1 fragments as R8) -> 24 MFMAs/8 steps (was 24/step).
//   waves 8-11(G2): per-step hw1 = W_hh1.h2(j-1) -> L1 gates (+xw1 chunk,
//                   +b_ih1) -> h2(j), j = iter-9 (lag 9).
// One barrier per iter; all cross-wave LDS is parity/chunk double-buffered.
// MFMA drain/step: 288 -> 204 per block. Tail: scoring for this cluster.
// ---------------------------------------------------------------------------
__global__ __launch_bounds__(768) void gru_fused_k(
    const float* __restrict__ xw0,          // sorted [Mtot+2CH][384] fp32
    const _Float16* __restrict__ pack,      // [3][24][4][64][8] f16 frags
    const float* __restrict__ b_hh0, const float* __restrict__ b_ih0,
    const float* __restrict__ b_ih1, const float* __restrict__ b_hh1,
    const int* __restrict__ starts, const int* __restrict__ len,
    const int* __restrict__ order, const float* __restrict__ sent,
    const float* __restrict__ lin_v, const float* __restrict__ scale,
    const float* __restrict__ lin_b, float* __restrict__ out) {
  const int c = blockIdx.x;
  const int t = threadIdx.x;
  const int wv = t >> 6, lane = t & 63;
  const int group = wv >> 2;                // 0:L0-hw  1:xw1-batch  2:L1-hw
  const int v = wv & 3;
  // ---- preload B fragments (96 VGPRs, loop-invariant, same as R8) ---------
  h8 B[6][4];
  {
    const _Float16* mp = pack + (size_t)group * (24 * 4 * 64 * 8);
#pragma unroll
    for (int i = 0; i < 6; ++i) {
      const int nt = (i >> 1) * 8 + 2 * v + (i & 1);
#pragma unroll
      for (int kt = 0; kt < 4; ++kt)
        B[i][kt] = *(const h8*)(mp + ((size_t)(nt * 4 + kt) * 64 + lane) * 8);
    }
  }
  const int L = len[c], start = starts[c];
  const int Lr = (L > 0) ? L : 1;
  const bool use_bih0 = (L == 0);
  // ---- LDS ----------------------------------------------------------------
  __shared__ __align__(16) float xwbuf[2 * CH * G3];     // 48 KB dbuf chunks
  __shared__ __align__(16) _Float16 ring[16][2 * RH];    // h1 ring, padded
  __shared__ __align__(16) _Float16 hp2[2][2][HH];       // h2 [par][hi/lo]
  __shared__ float xw1buf[2][8][G3];                     // [chunk&1][step][gate]
  __shared__ float ce_s[HH];
  __shared__ float vbuf[G3];
  __shared__ float sc_s[2048];
  __shared__ float sc_red;
  {
    _Float16* rp = &ring[0][0];
    for (int u = t; u < 16 * 2 * RH; u += 768) rp[u] = (_Float16)0.f;
  }
  if (t < HH) {
    hp2[0][0][t] = (_Float16)0.f; hp2[0][1][t] = (_Float16)0.f;
    hp2[1][0][t] = (_Float16)0.f; hp2[1][1][t] = (_Float16)0.f;
  }
  // prologue: stage xw0 chunk 0 into buffer 0
  if (!use_bih0) {
    const float4* src = (const float4*)(xw0 + (size_t)start * G3);
    float4* dst = (float4*)xwbuf;
    dst[t] = src[t];
    dst[t + 768] = src[t + 768];
  }
  // ---- per-lane gate constants (lanes 0..15) ------------------------------
  const int t0 = 32 * v + (lane & 15), t1 = t0 + 16;
  float bhr0 = 0.f, bhz0 = 0.f, bhn0 = 0.f, bhr1 = 0.f, bhz1 = 0.f, bhn1 = 0.f;
  float bir0 = 0.f, biz0 = 0.f, bin0 = 0.f, bir1 = 0.f, biz1 = 0.f, bin1 = 0.f;
  float ha = 0.f, hb = 0.f;                 // h1 slice (G0) / h2 slice (G2)
  if (lane < 16) {
    if (group == 0) {
      bhr0 = b_hh0[t0]; bhz0 = b_hh0[HH + t0]; bhn0 = b_hh0[2 * HH + t0];
      bhr1 = b_hh0[t1]; bhz1 = b_hh0[HH + t1]; bhn1 = b_hh0[2 * HH + t1];
      if (use_bih0) {
        bir0 = b_ih0[t0]; biz0 = b_ih0[HH + t0]; bin0 = b_ih0[2 * HH + t0];
        bir1 = b_ih0[t1]; biz1 = b_ih0[HH + t1]; bin1 = b_ih0[2 * HH + t1];
      }
    } else if (group == 2) {
      bhr0 = b_hh1[t0]; bhz0 = b_hh1[HH + t0]; bhn0 = b_hh1[2 * HH + t0];
      bhr1 = b_hh1[t1]; bhz1 = b_hh1[HH + t1]; bhn1 = b_hh1[2 * HH + t1];
      bir0 = b_ih1[t0]; biz0 = b_ih1[HH + t0]; bin0 = b_ih1[2 * HH + t0];
      bir1 = b_ih1[t1]; biz1 = b_ih1[HH + t1]; bin1 = b_ih1[2 * HH + t1];
    }
  }
  __syncthreads();   // init + chunk-0 staging visible
  const int q = lane >> 4;
  const int hs = ((lane & 15) == 0) ? 0 : 1;   // A row0 = h_hi, rows>=1 = h_lo
  for (int it2 = 0; it2 < Lr + 9; ++it2) {
    const int par = it2 & 1;
    // ---- prefetch next xw0 chunk (all threads) ---------------------------
    if (!use_bih0 && (it2 & (CH - 1)) == 0 && it2 + CH < Lr) {
      const float4* src = (const float4*)(xw0 + (size_t)(start + it2 + CH) * G3);
      float4* dst = (float4*)(xwbuf + ((((it2 >> 4) + 1) & 1) ? CH * G3 : 0));
      dst[t] = src[t];
      dst[t + 768] = src[t + 768];
    }
    if (group == 0) {
      if (it2 < Lr) {
        // A from ring slot (it2-1)&15 (hi for lane row0, lo for others)
        const _Float16* ab = &ring[(it2 - 1) & 15][hs * RH];
        h8 A[4];
#pragma unroll
        for (int kt = 0; kt < 4; ++kt)
          A[kt] = *(const h8*)(ab + kt * 32 + q * 8);
        f32x4 a0[6];
#pragma unroll
        for (int i = 0; i < 6; ++i) {
          f32x4 a = {0.f, 0.f, 0.f, 0.f};
#pragma unroll
          for (int kt = 0; kt < 4; ++kt)
            a = __builtin_amdgcn_mfma_f32_16x16x32_f16(A[kt], B[i][kt], a, 0, 0, 0);
          a0[i] = a;
        }
        if (lane < 16) {                     // L0 gates -> h1(it2)
          float xr0, xz0, xn0, xr1, xz1, xn1;
          if (use_bih0) {
            xr0 = bir0; xz0 = biz0; xn0 = bin0;
            xr1 = bir1; xz1 = biz1; xn1 = bin1;
          } else {
            const float* xrow = xwbuf + ((it2 >> 4) & 1) * (CH * G3)
                                      + (it2 & (CH - 1)) * G3;
            xr0 = xrow[t0]; xz0 = xrow[HH + t0]; xn0 = xrow[2 * HH + t0];
            xr1 = xrow[t1]; xz1 = xrow[HH + t1]; xn1 = xrow[2 * HH + t1];
          }
          const float hwr0 = a0[0][0] + a0[0][1];
          const float hwr1 = a0[1][0] + a0[1][1];
          const float hwz0 = a0[2][0] + a0[2][1];
          const float hwz1 = a0[3][0] + a0[3][1];
          const float hwn0 = a0[4][0] + a0[4][1];
          const float hwn1 = a0[5][0] + a0[5][1];
          const float r0 = 1.f / (1.f + __expf(-(xr0 + bhr0 + hwr0)));
          const float z0 = 1.f / (1.f + __expf(-(xz0 + bhz0 + hwz0)));
          const float r1 = 1.f / (1.f + __expf(-(xr1 + bhr1 + hwr1)));
          const float z1 = 1.f / (1.f + __expf(-(xz1 + bhz1 + hwz1)));
          float tg0 = xn0 + r0 * (bhn0 + hwn0);
          float tg1 = xn1 + r1 * (bhn1 + hwn1);
          tg0 = fminf(fmaxf(tg0, -15.f), 15.f);
          tg1 = fminf(fmaxf(tg1, -15.f), 15.f);
          const float e0 = __expf(2.f * tg0), e1 = __expf(2.f * tg1);
          const float n0 = (e0 - 1.f) / (e0 + 1.f);
          const float n1 = (e1 - 1.f) / (e1 + 1.f);
          ha = (1.f - z0) * n0 + z0 * ha;
          hb = (1.f - z1) * n1 + z1 * hb;
          const _Float16 hiA = (_Float16)ha, hiB = (_Float16)hb;
          _Float16* rs = &ring[it2 & 15][0];
          rs[t0] = hiA;      rs[RH + t0] = (_Float16)(ha - (float)hiA);
          rs[t1] = hiB;      rs[RH + t1] = (_Float16)(hb - (float)hiB);
        }
      }
    } else if (group == 1) {
      if (it2 >= 8 && (it2 & 7) == 0 && it2 - 8 < Lr) {
        // batched xw1 for chunk steps [it2-8, it2): A rows = 8 steps x hi/lo
        const int c8 = it2 - 8;
        const int m = lane & 15;
        const int s = m >> 1, half = m & 1;
        const _Float16* ab = &ring[(c8 + s) & 15][half * RH];
        h8 A[4];
#pragma unroll
        for (int kt = 0; kt < 4; ++kt)
          A[kt] = *(const h8*)(ab + kt * 32 + q * 8);
        const int cbuf = (c8 >> 3) & 1;
        float* xo0 = &xw1buf[cbuf][2 * q][0];       // step 2q  (rows 4q,4q+1)
        float* xo1 = &xw1buf[cbuf][2 * q + 1][0];   // step 2q+1(rows 4q+2,4q+3)
#pragma unroll
        for (int i = 0; i < 6; ++i) {
          f32x4 a = {0.f, 0.f, 0.f, 0.f};
#pragma unroll
          for (int kt = 0; kt < 4; ++kt)
            a = __builtin_amdgcn_mfma_f32_16x16x32_f16(A[kt], B[i][kt], a, 0, 0, 0);
          const int nt = (i >> 1) * 8 + 2 * v + (i & 1);
          const int col = nt * 16 + (lane & 15);
          xo0[col] = a[0] + a[1];
          xo1[col] = a[2] + a[3];
        }
      }
    } else {
      if (it2 >= 9) {                        // L1: j = it2 - 9
        const int j = it2 - 9;
        const _Float16* hbase = hp2[par][hs];
        h8 A[4];
#pragma unroll
        for (int kt = 0; kt < 4; ++kt)
          A[kt] = *(const h8*)(hbase + kt * 32 + q * 8);
        f32x4 a1[6];
#pragma unroll
        for (int i = 0; i < 6; ++i) {
          f32x4 a = {0.f, 0.f, 0.f, 0.f};
#pragma unroll
          for (int kt = 0; kt < 4; ++kt)
            a = __builtin_amdgcn_mfma_f32_16x16x32_f16(A[kt], B[i][kt], a, 0, 0, 0);
          a1[i] = a;
        }
        if (lane < 16) {
          const float* xi = xw1buf[(j >> 3) & 1][j & 7];
          const float xr0 = xi[t0] + bir0;
          const float xz0 = xi[HH + t0] + biz0;
          const float xn0 = xi[2 * HH + t0] + bin0;
          const float xr1 = xi[t1] + bir1;
          const float xz1 = xi[HH + t1] + biz1;
          const float xn1 = xi[2 * HH + t1] + bin1;
          const float hwr0 = a1[0][0] + a1[0][1];
          const float hwr1 = a1[1][0] + a1[1][1];
          const float hwz0 = a1[2][0] + a1[2][1];
          const float hwz1 = a1[3][0] + a1[3][1];
          const float hwn0 = a1[4][0] + a1[4][1];
          const float hwn1 = a1[5][0] + a1[5][1];
          const float r0 = 1.f / (1.f + __expf(-(xr0 + bhr0 + hwr0)));
          const float z0 = 1.f / (1.f + __expf(-(xz0 + bhz0 + hwz0)));
          const float r1 = 1.f / (1.f + __expf(-(xr1 + bhr1 + hwr1)));
          const float z1 = 1.f / (1.f + __expf(-(xz1 + bhz1 + hwz1)));
          float tg0 = xn0 + r0 * (bhn0 + hwn0);
          float tg1 = xn1 + r1 * (bhn1 + hwn1);
          tg0 = fminf(fmaxf(tg0, -15.f), 15.f);
          tg1 = fminf(fmaxf(tg1, -15.f), 15.f);
          const float e0 = __expf(2.f * tg0), e1 = __expf(2.f * tg1);
          const float n0 = (e0 - 1.f) / (e0 + 1.f);
          const float n1 = (e1 - 1.f) / (e1 + 1.f);
          ha = (1.f - z0) * n0 + z0 * ha;
          hb = (1.f - z1) * n1 + z1 * hb;
          const _Float16 hiA = (_Float16)ha, hiB = (_Float16)hb;
          hp2[par ^ 1][0][t0] = hiA;
          hp2[par ^ 1][1][t0] = (_Float16)(ha - (float)hiA);
          hp2[par ^ 1][0][t1] = hiB;
          hp2[par ^ 1][1][t1] = (_Float16)(hb - (float)hiB);
        }
      }
    }
    __syncthreads();   // the ONLY barrier per iter
  }
  // ---- scoring tail (cluster c's sentences) -------------------------------
  if (L == 0) return;
  if (group == 2 && lane < 16) { ce_s[t0] = ha; ce_s[t1] = hb; }
  if (t < G3) vbuf[t] = lin_v[t];
  __syncthreads();
  if (wv == 0) {   // ce . v[256:384] (per-cluster constant)
    float cd = ce_s[lane] * vbuf[DD + lane] + ce_s[64 + lane] * vbuf[DD + 64 + lane];
    for (int off = 32; off; off >>= 1) cd += __shfl_down(cd, off);
    if (lane == 0) sc_red = cd;
  }
  __syncthreads();
  const float cedot = sc_red;
  const float sc = scale[0], lb = lin_b[0];
  const int Lc = (L < 2048) ? L : 2048;
  for (int p = wv; p < Lc; p += 12) {
    const int i = order[c * NN + p];
    const float4 a = *(const float4*)(sent + (size_t)i * DD + lane * 4);
    const float4 b = ((const float4*)vbuf)[lane];
    float d = a.x * b.x + a.y * b.y + a.z * b.z + a.w * b.w;
    for (int off = 32; off; off >>= 1) d += __shfl_down(d, off);
    if (lane == 0) sc_s[p] = tanhf(sc * (d + cedot) + lb);
  }
  __syncthreads();
  if (wv == 0) {   // cluster sum -> 1/sum
    float s = 0.f;
    for (int p = lane; p < Lc; p += 64) s += sc_s[p];
    for (int off = 32; off; off >>= 1) s += __shfl_down(s, off);
    if (lane == 0) sc_red = 1.f / s;
  }
  __syncthreads();
  const float inv = sc_red;
  for (int p = t; p < Lc; p += 768) {
    const int i = order[c * NN + p];
    float ps = __expf(-(float)(i + 1) * 0.0625f);   // 1/4096^(1/3) == 1/16
    ps = fmaxf(0.5f, ps);
    out[i] = 0.5f * (sc_s[p] * inv) + 0.5f * ps;
  }
}

// ---------------------------------------------------------------------------
extern "C" void kernel_launch(void* const* d_in, const int* in_sizes, int n_in,
                              void* d_out, int out_size, void* d_ws, size_t ws_size,
                              hipStream_t stream) {
  const float* sent   = (const float*)d_in[0];
  const int*   labels = (const int*)d_in[1];
  const float* W_ih0  = (const float*)d_in[2];
  const float* W_hh0  = (const float*)d_in[3];
  const float* b_ih0  = (const float*)d_in[4];
  const float* b_hh0  = (const float*)d_in[5];
  const float* W_ih1  = (const float*)d_in[6];
  const float* W_hh1  = (const float*)d_in[7];
  const float* b_ih1  = (const float*)d_in[8];
  const float* b_hh1  = (const float*)d_in[9];
  const float* lin_v  = (const float*)d_in[10];
  const float* lin_g  = (const float*)d_in[11];
  const float* lin_b  = (const float*)d_in[12];
  float* out = (float*)d_out;

  char* ws = (char*)d_ws;
  size_t off = 0;
  auto alloc = [&](size_t bytes) -> void* {
    void* p = ws + off;
    off = (off + bytes + 255) & ~(size_t)255;
    return p;
  };
  int*   order  = (int*)  alloc((size_t)KK * NN * sizeof(int));
  int*   pos    = (int*)  alloc(NN * sizeof(int));
  int*   len    = (int*)  alloc(KK * sizeof(int));
  int*   starts = (int*)  alloc((KK + 1) * sizeof(int));
  float* scale  = (float*)alloc(sizeof(float));
  _Float16* pack = (_Float16*)alloc((size_t)18432 * 8 * sizeof(_Float16));
  float* xw     = (float*)alloc((size_t)(NN + KK + 2 * CH) * G3 * sizeof(float));
  (void)ws_size; (void)in_sizes; (void)n_in; (void)out_size;

  setup_k<<<dim3(19), dim3(1024), 0, stream>>>(
      labels, lin_v, lin_g, W_hh0, W_ih1, W_hh1,
      order, pos, len, starts, scale, pack);
  gemm_ih_k<<<dim3(32, 6), dim3(256), 0, stream>>>(
      sent, W_ih0, b_ih0, labels, pos, starts, xw);
  gru_fused_k<<<dim3(KK), dim3(768), 0, stream>>>(
      xw, pack, b_hh0, b_ih0, b_ih1, b_hh1, starts, len,
      order, sent, lin_v, scale, lin_b, out);
}